// Round 10
// baseline (615.042 us; speedup 1.0000x reference)
//
#include <hip/hip_runtime.h>
#include <stdint.h>

// SNN forward: conv1 -> scan -> pool1(fused) -> conv2 -> scan -> pool2(fused)
// -> conv3 -> scan -> fc -> reduce -> scan.
// Neuron: u=.75u+x; v=.96875v+u; s=(v>=100); v*=(1-s). Spikes u8 in d_ws.
// R8 lesson: don't fuse scan into conv (grid collapse + t-coalescing loss).
// R9 lesson: fc_gemm was LDS-issue-bound (0.5 B/FLOP, ds_read_b128 ~12cyc);
// fix = S operand in VGPRs from global (binary bytes), LDS carries W only.

#define T 128
#define AI 0.75f
#define AV 0.96875f
#define THETA 100.0f

__device__ __forceinline__ void neuron_step(float x, float& u, float& v, float& s) {
    u = AI * u + x;
    v = AV * v + u;
    s = (v >= THETA) ? 1.0f : 0.0f;
    v = v * (1.0f - s);
}

// ---------------- conv1 phase A: x[n][o][h][w][t], lanes over t -------------
__global__ __launch_bounds__(256) void conv1_x(
    const float* __restrict__ in, const float* __restrict__ cw,
    float* __restrict__ xout)
{
    int bid = blockIdx.x;                       // 12800
    int tIdx = (bid % 800) * 256 + threadIdx.x; // within [40][40][128]
    int n = bid / 800;
    int t  = tIdx % T;
    int wx = (tIdx / T) % 40;
    int hy = tIdx / (T * 40);

    float val[18];
    #pragma unroll
    for (int c = 0; c < 2; c++)
      #pragma unroll
      for (int dh = -1; dh <= 1; dh++)
        #pragma unroll
        for (int dw = -1; dw <= 1; dw++) {
            int q = c * 9 + (dh + 1) * 3 + (dw + 1);
            int hh = hy + dh, ww = wx + dw;
            bool ok = (hh >= 0) && (hh < 40) && (ww >= 0) && (ww < 40);
            val[q] = ok ? in[(((n * 2 + c) * 40 + hh) * 40 + ww) * T + t] : 0.0f;
        }

    #pragma unroll 1
    for (int o = 0; o < 8; o++) {
        const float* wp = cw + o * 18;          // uniform -> s_load
        float a = 0.f;
        #pragma unroll
        for (int q = 0; q < 18; q++) a += wp[q] * val[q];
        xout[(((n * 8 + o) * 40 + hy) * 40 + wx) * T + t] = a * 20.0f;
    }
}

// ---------------- scan (transposed via LDS): fp32 x rows -> u8 spikes -------
__global__ __launch_bounds__(256) void scan_spike_t(
    const float* __restrict__ x, uint8_t* __restrict__ out)
{
    __shared__ float lds[256 * 20];
    int tid = threadIdx.x;
    size_t r0 = (size_t)blockIdx.x * 256;
    const float* xb = x + r0 * T;

    float u = 0.f, v = 0.f;
    uint32_t ob[32];

    #pragma unroll
    for (int tb = 0; tb < 8; tb++) {
        __syncthreads();
        #pragma unroll
        for (int k = 0; k < 4; k++) {
            int f = tid + k * 256;
            int row = f >> 2, q = f & 3;
            float4 vv = *(const float4*)(xb + (size_t)row * T + tb * 16 + q * 4);
            *(float4*)&lds[row * 20 + q * 4] = vv;
        }
        __syncthreads();
        #pragma unroll
        for (int k = 0; k < 4; k++) {
            float4 xv = *(const float4*)&lds[tid * 20 + k * 4];
            float s0, s1, s2, s3;
            neuron_step(xv.x, u, v, s0); neuron_step(xv.y, u, v, s1);
            neuron_step(xv.z, u, v, s2); neuron_step(xv.w, u, v, s3);
            ob[tb * 4 + k] = (uint32_t)s0 | ((uint32_t)s1 << 8) |
                             ((uint32_t)s2 << 16) | ((uint32_t)s3 << 24);
        }
    }

    uint32_t* op = (uint32_t*)(out + (r0 + tid) * T);
    #pragma unroll
    for (int k = 0; k < 8; k++)
        *(uint4*)&op[k * 4] = make_uint4(ob[k*4], ob[k*4+1], ob[k*4+2], ob[k*4+3]);
}

// ---------------- pool fused: 2x2 sum (u8 adds, no carry) + scan + delay ----
template<int C, int HO, int WO>
__global__ __launch_bounds__(256) void pool_fused(
    const uint8_t* __restrict__ in, const float* __restrict__ pw_ptr,
    uint8_t* __restrict__ out)
{
    __shared__ uint32_t lds[256 * 20];
    int tid = threadIdx.x;
    size_t r0 = (size_t)blockIdx.x * 256;
    float pw = pw_ptr[0];

    float u = 0.f, v = 0.f;
    uint32_t ob[32];
    uint32_t carry = 0;

    #pragma unroll
    for (int tb = 0; tb < 2; tb++) {
        __syncthreads();
        #pragma unroll
        for (int k = 0; k < 4; k++) {
            int f = tid + k * 256;
            int row = f >> 2, q = f & 3;
            int orow = (int)r0 + row;
            int wx = orow % WO;
            int hy = (orow / WO) % HO;
            int c  = (orow / (WO * HO)) % C;
            int nn = orow / (WO * HO * C);
            const uint8_t* p00 = in +
                (((size_t)(nn * C + c) * (2 * HO) + 2 * hy) * (2 * WO) + 2 * wx) * T;
            int off = tb * 64 + q * 16;
            uint4 a = *(const uint4*)(p00 + off);
            uint4 b = *(const uint4*)(p00 + T + off);
            uint4 cc = *(const uint4*)(p00 + 2 * WO * T + off);
            uint4 d = *(const uint4*)(p00 + 2 * WO * T + T + off);
            *(uint4*)&lds[row * 20 + q * 4] =
                make_uint4(a.x + b.x + cc.x + d.x, a.y + b.y + cc.y + d.y,
                           a.z + b.z + cc.z + d.z, a.w + b.w + cc.w + d.w);
        }
        __syncthreads();
        #pragma unroll
        for (int q = 0; q < 4; q++) {
            uint4 w = *(const uint4*)&lds[tid * 20 + q * 4];
            uint32_t words[4] = {w.x, w.y, w.z, w.w};
            #pragma unroll
            for (int j = 0; j < 4; j++) {
                uint32_t cur = words[j];
                uint32_t del = (cur << 8) | carry;   // delay_shift bytes
                carry = cur >> 24;
                float s0, s1, s2, s3;
                neuron_step(pw * (float)(del & 0xffu),         u, v, s0);
                neuron_step(pw * (float)((del >> 8) & 0xffu),  u, v, s1);
                neuron_step(pw * (float)((del >> 16) & 0xffu), u, v, s2);
                neuron_step(pw * (float)((del >> 24) & 0xffu), u, v, s3);
                ob[tb * 16 + q * 4 + j] = (uint32_t)s0 | ((uint32_t)s1 << 8) |
                                          ((uint32_t)s2 << 16) | ((uint32_t)s3 << 24);
            }
        }
    }

    uint32_t* op = (uint32_t*)(out + (r0 + tid) * T);
    #pragma unroll
    for (int k = 0; k < 8; k++)
        *(uint4*)&op[k * 4] = make_uint4(ob[k*4], ob[k*4+1], ob[k*4+2], ob[k*4+3]);
}

// ---------------- conv phase A (grouped): COUT_PER outputs per thread -------
template<int CIN, int COUT_PER, int G, int H, int W>
__global__ __launch_bounds__(256) void conv_x_all(
    const uint8_t* __restrict__ in, const float* __restrict__ cw, float scale,
    float* __restrict__ xout)
{
    constexpr int BPG = H * W * T / 256;
    int bid = blockIdx.x;
    int tIdx = (bid % BPG) * 256 + threadIdx.x;
    int gn = bid / BPG;
    int g = gn % G;                             // uniform
    int n = gn / G;                             // uniform
    int t  = tIdx % T;
    int wx = (tIdx / T) % W;
    int hy = tIdx / (T * W);

    int tm = (t == 0) ? 0 : (t - 1);
    float tmask = (t == 0) ? 0.0f : 1.0f;

    bool okh[3] = {hy > 0, true, hy < H - 1};
    bool okw[3] = {wx > 0, true, wx < W - 1};

    const uint8_t* base = in + ((n * CIN * H + hy) * W + wx) * T + tm;
    const float* wbase = cw + g * COUT_PER * CIN * 9;

    float acc[COUT_PER];
    #pragma unroll
    for (int oi = 0; oi < COUT_PER; oi++) acc[oi] = 0.f;

    #pragma unroll 1
    for (int c = 0; c < CIN; c++) {
        float tap[9];
        #pragma unroll
        for (int dh = 0; dh < 3; dh++)
            #pragma unroll
            for (int dw = 0; dw < 3; dw++) {
                bool ok = okh[dh] && okw[dw];
                tap[dh * 3 + dw] = ok ?
                    (float)base[(c * H * W + (dh - 1) * W + (dw - 1)) * T] : 0.f;
            }
        #pragma unroll
        for (int oi = 0; oi < COUT_PER; oi++) {
            if ((oi & 3) == 0) __builtin_amdgcn_sched_barrier(0);
            const float* wp = wbase + (oi * CIN + c) * 9;
            float a = acc[oi];
            #pragma unroll
            for (int q = 0; q < 9; q++) a += wp[q] * tap[q];
            acc[oi] = a;
        }
    }

    float sm = scale * tmask;
    #pragma unroll
    for (int oi = 0; oi < COUT_PER; oi++) {
        int o = g * COUT_PER + oi;
        xout[((n * (G * COUT_PER) + o) * H * W + hy * W + wx) * T + t] = acc[oi] * sm;
    }
}

// ---------------- W transpose: fwT[c][o] = fw[o][c] -------------------------
__global__ __launch_bounds__(256) void transpose_w(
    const float* __restrict__ fw, float* __restrict__ fwT)
{
    __shared__ float tile[32][33];
    int bc = blockIdx.x % 100;
    int bo = blockIdx.x / 100;
    int lx = threadIdx.x & 31;
    int ly = threadIdx.x >> 5;
    #pragma unroll
    for (int k = 0; k < 4; k++)
        tile[ly + 8 * k][lx] = fw[(bo * 32 + ly + 8 * k) * 3200 + bc * 32 + lx];
    __syncthreads();
    #pragma unroll
    for (int k = 0; k < 4; k++)
        fwT[(bc * 32 + ly + 8 * k) * 512 + bo * 32 + lx] = tile[lx][ly + 8 * k];
}

// ---------------- FC GEMM (split 8): W via LDS, S via VGPR bytes ------------
// Per cc the inner loop reads only 2x ds_read_b128 (W); S comes from per-thread
// registers loaded directly from global u8 (16 og-lanes share addrs -> L1
// broadcast). Register shift window provides the t-1 delay (replaces shfl).
#define FC_CC 40
#define FC_ROW 140
#define FC_CRANGE 400

__global__ __launch_bounds__(256) void fc_gemm(
    const uint8_t* __restrict__ s5,   // [16][3200][128]
    const float* __restrict__ fwT,    // [3200][512]
    float* __restrict__ ypart)        // [8][16][128][512]
{
    __shared__ float ldsW[FC_CC * FC_ROW];

    int bid = blockIdx.x;
    int ks = bid & 7;
    int n  = (bid >> 3) & 15;
    int ob = bid >> 7;                // 0..3
    int o0 = ob * 128;
    int cbase = ks * FC_CRANGE;

    int tid = threadIdx.x;
    int og = tid & 15;
    int tg = tid >> 4;
    int wo = og * 8 + ((og >> 2) << 2);

    int srow = tid >> 5;              // 0..7 (W staging)
    int scol = tid & 31;              // 0..31
    int sw   = scol * 4 + ((scol >> 3) << 2);

    const uint8_t* sbase = s5 + (size_t)n * 3200 * T + tg * 8;

    float acc[8][8];
    #pragma unroll
    for (int i = 0; i < 8; i++)
        #pragma unroll
        for (int j = 0; j < 8; j++) acc[i][j] = 0.f;

    float4 wr4[5];
    uint32_t sloA[20], shiA[20], sloB[20], shiB[20];

    // S loader: window [t-1 .. t+6] for this thread's 8 t's, c = cb+q
    #define LOAD_S(LO, HI, cb)                                              \
        _Pragma("unroll")                                                   \
        for (int q = 0; q < 20; q++) {                                      \
            const uint8_t* sp = sbase + (size_t)((cb) + q) * T;             \
            uint64_t bc2 = *(const uint64_t*)sp;                            \
            uint32_t B = (uint32_t)bc2, C = (uint32_t)(bc2 >> 32);          \
            uint32_t A = (tg > 0) ? *(const uint32_t*)(sp - 4) : 0u;        \
            LO[q] = (uint32_t)(((uint64_t)B << 8) | (A >> 24));             \
            HI[q] = (uint32_t)(((uint64_t)C << 8) | (B >> 24));             \
        }

    // preload W chunk 0 + S chunk 0 sub 0
    #pragma unroll
    for (int p = 0; p < 5; p++) {
        int c = cbase + p * 8 + srow;
        wr4[p] = *(const float4*)(fwT + (size_t)c * 512 + o0 + scol * 4);
    }
    LOAD_S(sloA, shiA, cbase)

    for (int ch = 0; ch < 10; ch++) {
        __syncthreads();
        #pragma unroll
        for (int p = 0; p < 5; p++)
            *(float4*)&ldsW[(p * 8 + srow) * FC_ROW + sw] = wr4[p];
        __syncthreads();
        if (ch < 9) {
            int c0 = cbase + (ch + 1) * FC_CC;
            #pragma unroll
            for (int p = 0; p < 5; p++) {
                int c = c0 + p * 8 + srow;
                wr4[p] = *(const float4*)(fwT + (size_t)c * 512 + o0 + scol * 4);
            }
        }
        LOAD_S(sloB, shiB, cbase + ch * FC_CC + 20)   // sub1 (in flight over sub0)
        #pragma unroll 4
        for (int q = 0; q < 20; q++) {
            const float* wr = &ldsW[q * FC_ROW + wo];
            float4 w0 = *(const float4*)(wr);
            float4 w1 = *(const float4*)(wr + 4);
            float wv[8] = {w0.x, w0.y, w0.z, w0.w, w1.x, w1.y, w1.z, w1.w};
            uint32_t lo = sloA[q], hi = shiA[q];
            float sv[8] = {(float)(lo & 0xffu), (float)((lo >> 8) & 0xffu),
                           (float)((lo >> 16) & 0xffu), (float)(lo >> 24),
                           (float)(hi & 0xffu), (float)((hi >> 8) & 0xffu),
                           (float)((hi >> 16) & 0xffu), (float)(hi >> 24)};
            #pragma unroll
            for (int i = 0; i < 8; i++)
                #pragma unroll
                for (int j = 0; j < 8; j++)
                    acc[i][j] += wv[i] * sv[j];
        }
        if (ch < 9) LOAD_S(sloA, shiA, cbase + (ch + 1) * FC_CC)  // next sub0
        #pragma unroll 4
        for (int q = 0; q < 20; q++) {
            const float* wr = &ldsW[(20 + q) * FC_ROW + wo];
            float4 w0 = *(const float4*)(wr);
            float4 w1 = *(const float4*)(wr + 4);
            float wv[8] = {w0.x, w0.y, w0.z, w0.w, w1.x, w1.y, w1.z, w1.w};
            uint32_t lo = sloB[q], hi = shiB[q];
            float sv[8] = {(float)(lo & 0xffu), (float)((lo >> 8) & 0xffu),
                           (float)((lo >> 16) & 0xffu), (float)(lo >> 24),
                           (float)(hi & 0xffu), (float)((hi >> 8) & 0xffu),
                           (float)((hi >> 16) & 0xffu), (float)(hi >> 24)};
            #pragma unroll
            for (int i = 0; i < 8; i++)
                #pragma unroll
                for (int j = 0; j < 8; j++)
                    acc[i][j] += wv[i] * sv[j];
        }
    }
    #undef LOAD_S

    float* yp = ypart + ((size_t)(ks * 16 + n) * T) * 512;
    #pragma unroll
    for (int j = 0; j < 8; j++) {
        int t = tg * 8 + j;
        float4 v0 = make_float4(acc[0][j], acc[1][j], acc[2][j], acc[3][j]);
        float4 v1 = make_float4(acc[4][j], acc[5][j], acc[6][j], acc[7][j]);
        *(float4*)&yp[t * 512 + o0 + og * 8]     = v0;
        *(float4*)&yp[t * 512 + o0 + og * 8 + 4] = v1;
    }
}

// ---------------- FC partial reduce (8 partials, float4) --------------------
__global__ __launch_bounds__(256) void fc_reduce(
    const float4* __restrict__ yp, float4* __restrict__ ys)
{
    int id = blockIdx.x * 256 + threadIdx.x;          // 262,144
    float4 x = yp[id];
    #pragma unroll
    for (int k = 1; k < 8; k++) {
        float4 y = yp[(size_t)k * 262144 + id];
        x.x += y.x; x.y += y.y; x.z += y.z; x.w += y.w;
    }
    ys[id] = x;
}

__global__ __launch_bounds__(64) void fc_scan(
    const float* __restrict__ ysum,   // [16][128][512]
    float* __restrict__ out)          // [16][512][128]
{
    int id = blockIdx.x * 64 + threadIdx.x;           // 8192
    int o = id & 511;
    int n = id >> 9;
    float u = 0.f, v = 0.f;
    float prev = 0.f;                 // final delay_shift
    for (int tb = 0; tb < T / 4; tb++) {
        float b0, b1, b2, b3;
        float x, s;
        x = ysum[(n * T + tb * 4 + 0) * 512 + o]; neuron_step(x, u, v, s); b0 = prev; prev = s;
        x = ysum[(n * T + tb * 4 + 1) * 512 + o]; neuron_step(x, u, v, s); b1 = prev; prev = s;
        x = ysum[(n * T + tb * 4 + 2) * 512 + o]; neuron_step(x, u, v, s); b2 = prev; prev = s;
        x = ysum[(n * T + tb * 4 + 3) * 512 + o]; neuron_step(x, u, v, s); b3 = prev; prev = s;
        *(float4*)&out[((size_t)(n * 512 + o)) * T + tb * 4] = make_float4(b0, b1, b2, b3);
    }
}

// ---------------- launch ----------------------------------------------------
extern "C" void kernel_launch(void* const* d_in, const int* in_sizes, int n_in,
                              void* d_out, int out_size, void* d_ws, size_t ws_size,
                              hipStream_t stream) {
    const float* spike = (const float*)d_in[0];   // [16][2][40][40][128]
    const float* c1w   = (const float*)d_in[1];   // [8][2][3][3]
    const float* c2w   = (const float*)d_in[2];   // [16][8][3][3]
    const float* c3w   = (const float*)d_in[3];   // [32][16][3][3]
    const float* p1w   = (const float*)d_in[4];   // scalar
    const float* p2w   = (const float*)d_in[5];   // scalar
    const float* fcw   = (const float*)d_in[6];   // [512][3200]
    float* out = (float*)d_out;                   // [16][512][128]

    char* ws = (char*)d_ws;
    // spike buffers
    uint8_t* s1 = (uint8_t*)(ws);                 // 26,214,400
    uint8_t* s2 = (uint8_t*)(ws + 26214400);      //  6,553,600
    uint8_t* s3 = (uint8_t*)(ws + 32768000);      // 13,107,200
    uint8_t* s4 = (uint8_t*)(ws + 45875200);      //  3,276,800
    uint8_t* s5 = (uint8_t*)(ws + 49152000);      //  6,553,600 (ends 55,705,600)
    // region @55,705,600: xbuf1 (104,857,600) -> xbuf (52,428,800) ->
    // ypart (33,554,432). Sequentially dead, safe aliases.
    float* xbuf1 = (float*)(ws + 55705600);
    float* xbuf  = (float*)(ws + 55705600);
    float* ypart = (float*)(ws + 55705600);
    float* ysumb = (float*)(ws + 122814464);      //  4,194,304 (ends 127,008,768)
    float* fwT   = (float*)(ws + 160563200);      //  6,553,600 (ends 167,116,800)

    conv1_x<<<12800, 256, 0, stream>>>(spike, c1w, xbuf1);
    scan_spike_t<<<800, 256, 0, stream>>>(xbuf1, s1);
    transpose_w<<<1600, 256, 0, stream>>>(fcw, fwT);

    pool_fused<8, 20, 20><<<200, 256, 0, stream>>>(s1, p1w, s2);
    conv_x_all<8, 16, 1, 20, 20><<<3200, 256, 0, stream>>>(s2, c2w, 100.0f, xbuf);
    scan_spike_t<<<400, 256, 0, stream>>>(xbuf, s3);

    pool_fused<16, 10, 10><<<100, 256, 0, stream>>>(s3, p2w, s4);
    conv_x_all<16, 16, 2, 10, 10><<<1600, 256, 0, stream>>>(s4, c3w, 100.0f, xbuf);
    scan_spike_t<<<200, 256, 0, stream>>>(xbuf, s5);

    fc_gemm<<<512, 256, 0, stream>>>(s5, fwT, ypart);
    fc_reduce<<<1024, 256, 0, stream>>>((const float4*)ypart, (float4*)ysumb);
    fc_scan<<<128, 64, 0, stream>>>(ysumb, out);
}

// Round 11
// 538.012 us; speedup vs baseline: 1.1432x; 1.1432x over previous
//
#include <hip/hip_runtime.h>
#include <stdint.h>

// SNN forward: conv1 -> scan -> pool1(fused) -> conv2 -> scan -> pool2(fused)
// -> conv3 -> scan -> fc -> reduce -> scan.
// Neuron: u=.75u+x; v=.96875v+u; s=(v>=100); v*=(1-s). Spikes u8 in d_ws.
// R8: don't fuse scan into conv (grid collapse + t-coalescing loss).
// R9/R10: fc_gemm LDS-bound at 0.5 B/FLOP; register-gather S was VMEM-bound.
// R11: wave-uniform W (8 o/wave, shared-address float4) + lane-contiguous S
//      (t=lane, coalesced u8, delay via lane-1 offset) -> no LDS at all.

#define T 128
#define AI 0.75f
#define AV 0.96875f
#define THETA 100.0f

__device__ __forceinline__ void neuron_step(float x, float& u, float& v, float& s) {
    u = AI * u + x;
    v = AV * v + u;
    s = (v >= THETA) ? 1.0f : 0.0f;
    v = v * (1.0f - s);
}

// ---------------- conv1 phase A: x[n][o][h][w][t], lanes over t -------------
__global__ __launch_bounds__(256) void conv1_x(
    const float* __restrict__ in, const float* __restrict__ cw,
    float* __restrict__ xout)
{
    int bid = blockIdx.x;                       // 12800
    int tIdx = (bid % 800) * 256 + threadIdx.x; // within [40][40][128]
    int n = bid / 800;
    int t  = tIdx % T;
    int wx = (tIdx / T) % 40;
    int hy = tIdx / (T * 40);

    float val[18];
    #pragma unroll
    for (int c = 0; c < 2; c++)
      #pragma unroll
      for (int dh = -1; dh <= 1; dh++)
        #pragma unroll
        for (int dw = -1; dw <= 1; dw++) {
            int q = c * 9 + (dh + 1) * 3 + (dw + 1);
            int hh = hy + dh, ww = wx + dw;
            bool ok = (hh >= 0) && (hh < 40) && (ww >= 0) && (ww < 40);
            val[q] = ok ? in[(((n * 2 + c) * 40 + hh) * 40 + ww) * T + t] : 0.0f;
        }

    #pragma unroll 1
    for (int o = 0; o < 8; o++) {
        const float* wp = cw + o * 18;          // uniform -> s_load
        float a = 0.f;
        #pragma unroll
        for (int q = 0; q < 18; q++) a += wp[q] * val[q];
        xout[(((n * 8 + o) * 40 + hy) * 40 + wx) * T + t] = a * 20.0f;
    }
}

// ---------------- scan (transposed via LDS): fp32 x rows -> u8 spikes -------
__global__ __launch_bounds__(256) void scan_spike_t(
    const float* __restrict__ x, uint8_t* __restrict__ out)
{
    __shared__ float lds[256 * 20];
    int tid = threadIdx.x;
    size_t r0 = (size_t)blockIdx.x * 256;
    const float* xb = x + r0 * T;

    float u = 0.f, v = 0.f;
    uint32_t ob[32];

    #pragma unroll
    for (int tb = 0; tb < 8; tb++) {
        __syncthreads();
        #pragma unroll
        for (int k = 0; k < 4; k++) {
            int f = tid + k * 256;
            int row = f >> 2, q = f & 3;
            float4 vv = *(const float4*)(xb + (size_t)row * T + tb * 16 + q * 4);
            *(float4*)&lds[row * 20 + q * 4] = vv;
        }
        __syncthreads();
        #pragma unroll
        for (int k = 0; k < 4; k++) {
            float4 xv = *(const float4*)&lds[tid * 20 + k * 4];
            float s0, s1, s2, s3;
            neuron_step(xv.x, u, v, s0); neuron_step(xv.y, u, v, s1);
            neuron_step(xv.z, u, v, s2); neuron_step(xv.w, u, v, s3);
            ob[tb * 4 + k] = (uint32_t)s0 | ((uint32_t)s1 << 8) |
                             ((uint32_t)s2 << 16) | ((uint32_t)s3 << 24);
        }
    }

    uint32_t* op = (uint32_t*)(out + (r0 + tid) * T);
    #pragma unroll
    for (int k = 0; k < 8; k++)
        *(uint4*)&op[k * 4] = make_uint4(ob[k*4], ob[k*4+1], ob[k*4+2], ob[k*4+3]);
}

// ---------------- pool fused: 2x2 sum (u8 adds, no carry) + scan + delay ----
template<int C, int HO, int WO>
__global__ __launch_bounds__(256) void pool_fused(
    const uint8_t* __restrict__ in, const float* __restrict__ pw_ptr,
    uint8_t* __restrict__ out)
{
    __shared__ uint32_t lds[256 * 20];
    int tid = threadIdx.x;
    size_t r0 = (size_t)blockIdx.x * 256;
    float pw = pw_ptr[0];

    float u = 0.f, v = 0.f;
    uint32_t ob[32];
    uint32_t carry = 0;

    #pragma unroll
    for (int tb = 0; tb < 2; tb++) {
        __syncthreads();
        #pragma unroll
        for (int k = 0; k < 4; k++) {
            int f = tid + k * 256;
            int row = f >> 2, q = f & 3;
            int orow = (int)r0 + row;
            int wx = orow % WO;
            int hy = (orow / WO) % HO;
            int c  = (orow / (WO * HO)) % C;
            int nn = orow / (WO * HO * C);
            const uint8_t* p00 = in +
                (((size_t)(nn * C + c) * (2 * HO) + 2 * hy) * (2 * WO) + 2 * wx) * T;
            int off = tb * 64 + q * 16;
            uint4 a = *(const uint4*)(p00 + off);
            uint4 b = *(const uint4*)(p00 + T + off);
            uint4 cc = *(const uint4*)(p00 + 2 * WO * T + off);
            uint4 d = *(const uint4*)(p00 + 2 * WO * T + T + off);
            *(uint4*)&lds[row * 20 + q * 4] =
                make_uint4(a.x + b.x + cc.x + d.x, a.y + b.y + cc.y + d.y,
                           a.z + b.z + cc.z + d.z, a.w + b.w + cc.w + d.w);
        }
        __syncthreads();
        #pragma unroll
        for (int q = 0; q < 4; q++) {
            uint4 w = *(const uint4*)&lds[tid * 20 + q * 4];
            uint32_t words[4] = {w.x, w.y, w.z, w.w};
            #pragma unroll
            for (int j = 0; j < 4; j++) {
                uint32_t cur = words[j];
                uint32_t del = (cur << 8) | carry;   // delay_shift bytes
                carry = cur >> 24;
                float s0, s1, s2, s3;
                neuron_step(pw * (float)(del & 0xffu),         u, v, s0);
                neuron_step(pw * (float)((del >> 8) & 0xffu),  u, v, s1);
                neuron_step(pw * (float)((del >> 16) & 0xffu), u, v, s2);
                neuron_step(pw * (float)((del >> 24) & 0xffu), u, v, s3);
                ob[tb * 16 + q * 4 + j] = (uint32_t)s0 | ((uint32_t)s1 << 8) |
                                          ((uint32_t)s2 << 16) | ((uint32_t)s3 << 24);
            }
        }
    }

    uint32_t* op = (uint32_t*)(out + (r0 + tid) * T);
    #pragma unroll
    for (int k = 0; k < 8; k++)
        *(uint4*)&op[k * 4] = make_uint4(ob[k*4], ob[k*4+1], ob[k*4+2], ob[k*4+3]);
}

// ---------------- conv phase A (grouped): COUT_PER outputs per thread -------
template<int CIN, int COUT_PER, int G, int H, int W>
__global__ __launch_bounds__(256) void conv_x_all(
    const uint8_t* __restrict__ in, const float* __restrict__ cw, float scale,
    float* __restrict__ xout)
{
    constexpr int BPG = H * W * T / 256;
    int bid = blockIdx.x;
    int tIdx = (bid % BPG) * 256 + threadIdx.x;
    int gn = bid / BPG;
    int g = gn % G;                             // uniform
    int n = gn / G;                             // uniform
    int t  = tIdx % T;
    int wx = (tIdx / T) % W;
    int hy = tIdx / (T * W);

    int tm = (t == 0) ? 0 : (t - 1);
    float tmask = (t == 0) ? 0.0f : 1.0f;

    bool okh[3] = {hy > 0, true, hy < H - 1};
    bool okw[3] = {wx > 0, true, wx < W - 1};

    const uint8_t* base = in + ((n * CIN * H + hy) * W + wx) * T + tm;
    const float* wbase = cw + g * COUT_PER * CIN * 9;

    float acc[COUT_PER];
    #pragma unroll
    for (int oi = 0; oi < COUT_PER; oi++) acc[oi] = 0.f;

    #pragma unroll 1
    for (int c = 0; c < CIN; c++) {
        float tap[9];
        #pragma unroll
        for (int dh = 0; dh < 3; dh++)
            #pragma unroll
            for (int dw = 0; dw < 3; dw++) {
                bool ok = okh[dh] && okw[dw];
                tap[dh * 3 + dw] = ok ?
                    (float)base[(c * H * W + (dh - 1) * W + (dw - 1)) * T] : 0.f;
            }
        #pragma unroll
        for (int oi = 0; oi < COUT_PER; oi++) {
            if ((oi & 3) == 0) __builtin_amdgcn_sched_barrier(0);
            const float* wp = wbase + (oi * CIN + c) * 9;
            float a = acc[oi];
            #pragma unroll
            for (int q = 0; q < 9; q++) a += wp[q] * tap[q];
            acc[oi] = a;
        }
    }

    float sm = scale * tmask;
    #pragma unroll
    for (int oi = 0; oi < COUT_PER; oi++) {
        int o = g * COUT_PER + oi;
        xout[((n * (G * COUT_PER) + o) * H * W + hy * W + wx) * T + t] = acc[oi] * sm;
    }
}

// ---------------- W transpose: fwT[c][o] = fw[o][c] -------------------------
__global__ __launch_bounds__(256) void transpose_w(
    const float* __restrict__ fw, float* __restrict__ fwT)
{
    __shared__ float tile[32][33];
    int bc = blockIdx.x % 100;
    int bo = blockIdx.x / 100;
    int lx = threadIdx.x & 31;
    int ly = threadIdx.x >> 5;
    #pragma unroll
    for (int k = 0; k < 4; k++)
        tile[ly + 8 * k][lx] = fw[(bo * 32 + ly + 8 * k) * 3200 + bc * 32 + lx];
    __syncthreads();
    #pragma unroll
    for (int k = 0; k < 4; k++)
        fwT[(bc * 32 + ly + 8 * k) * 512 + bo * 32 + lx] = tile[lx][ly + 8 * k];
}

// ---------------- FC GEMM (no LDS): ypart[ks][n][o][t] ----------------------
// Wave owns 8 consecutive o (W loads: one shared address/line), lane owns
// t=lane and t=lane+64 (S loads: coalesced u8; delay via lane-1 / lane+63).
#define FC_CRANGE 400

__global__ __launch_bounds__(256) void fc_gemm(
    const uint8_t* __restrict__ s5,   // [16][3200][128]
    const float* __restrict__ fwT,    // [3200][512]
    float* __restrict__ ypart)        // [8][16][512][128]
{
    int bid = blockIdx.x;             // 2048
    int ks = bid & 7;
    int n  = (bid >> 3) & 15;
    int ob = bid >> 7;                // 0..15
    int lane = threadIdx.x & 63;
    int wv   = threadIdx.x >> 6;      // 0..3
    int o0 = ob * 32 + wv * 8;
    int cbase = ks * FC_CRANGE;

    const uint8_t* sp = s5 + ((size_t)n * 3200 + cbase) * T;
    const float*   wp = fwT + (size_t)cbase * 512 + o0;

    float acc[8][2];
    #pragma unroll
    for (int i = 0; i < 8; i++) { acc[i][0] = 0.f; acc[i][1] = 0.f; }

    bool l0 = (lane == 0);

    #pragma unroll 4
    for (int c = 0; c < FC_CRANGE; c++) {
        uint8_t r0 = sp[c * T + lane - 1];       // t-1 for t=lane (lane0 masked)
        uint8_t r1 = sp[c * T + lane + 63];      // t-1 for t=lane+64
        float4 wA = *(const float4*)(wp + c * 512);
        float4 wB = *(const float4*)(wp + c * 512 + 4);
        float f0 = l0 ? 0.f : (float)r0;
        float f1 = (float)r1;
        float w[8] = {wA.x, wA.y, wA.z, wA.w, wB.x, wB.y, wB.z, wB.w};
        #pragma unroll
        for (int i = 0; i < 8; i++) {
            acc[i][0] += w[i] * f0;
            acc[i][1] += w[i] * f1;
        }
    }

    float* yp = ypart + ((size_t)(ks * 16 + n) * 512 + o0) * T;
    #pragma unroll
    for (int i = 0; i < 8; i++) {
        yp[i * T + lane]      = acc[i][0];
        yp[i * T + lane + 64] = acc[i][1];
    }
}

// ---------------- FC partial reduce (8 partials, float4) --------------------
__global__ __launch_bounds__(256) void fc_reduce(
    const float4* __restrict__ yp, float4* __restrict__ ys)
{
    int id = blockIdx.x * 256 + threadIdx.x;          // 262,144
    float4 x = yp[id];
    #pragma unroll
    for (int k = 1; k < 8; k++) {
        float4 y = yp[(size_t)k * 262144 + id];
        x.x += y.x; x.y += y.y; x.z += y.z; x.w += y.w;
    }
    ys[id] = x;
}

// ---------------- FC scan (transposed LDS, fp32 out w/ delay) ---------------
// x rows = (n,o): [8192][128]; out same layout = d_out [16][512][128].
__global__ __launch_bounds__(256) void fc_scan_t(
    const float* __restrict__ x, float* __restrict__ out)
{
    __shared__ float lds[256 * 20];
    int tid = threadIdx.x;
    size_t r0 = (size_t)blockIdx.x * 256;
    const float* xb = x + r0 * T;
    float* op = out + (r0 + tid) * T;

    float u = 0.f, v = 0.f;
    float prev = 0.f;                 // final delay_shift

    #pragma unroll
    for (int tb = 0; tb < 8; tb++) {
        __syncthreads();
        #pragma unroll
        for (int k = 0; k < 4; k++) {
            int f = tid + k * 256;
            int row = f >> 2, q = f & 3;
            float4 vv = *(const float4*)(xb + (size_t)row * T + tb * 16 + q * 4);
            *(float4*)&lds[row * 20 + q * 4] = vv;
        }
        __syncthreads();
        #pragma unroll
        for (int k = 0; k < 4; k++) {
            float4 xv = *(const float4*)&lds[tid * 20 + k * 4];
            float s0, s1, s2, s3;
            neuron_step(xv.x, u, v, s0); neuron_step(xv.y, u, v, s1);
            neuron_step(xv.z, u, v, s2); neuron_step(xv.w, u, v, s3);
            *(float4*)&op[tb * 16 + k * 4] = make_float4(prev, s0, s1, s2);
            prev = s3;
        }
    }
}

// ---------------- launch ----------------------------------------------------
extern "C" void kernel_launch(void* const* d_in, const int* in_sizes, int n_in,
                              void* d_out, int out_size, void* d_ws, size_t ws_size,
                              hipStream_t stream) {
    const float* spike = (const float*)d_in[0];   // [16][2][40][40][128]
    const float* c1w   = (const float*)d_in[1];   // [8][2][3][3]
    const float* c2w   = (const float*)d_in[2];   // [16][8][3][3]
    const float* c3w   = (const float*)d_in[3];   // [32][16][3][3]
    const float* p1w   = (const float*)d_in[4];   // scalar
    const float* p2w   = (const float*)d_in[5];   // scalar
    const float* fcw   = (const float*)d_in[6];   // [512][3200]
    float* out = (float*)d_out;                   // [16][512][128]

    char* ws = (char*)d_ws;
    // spike buffers
    uint8_t* s1 = (uint8_t*)(ws);                 // 26,214,400
    uint8_t* s2 = (uint8_t*)(ws + 26214400);      //  6,553,600
    uint8_t* s3 = (uint8_t*)(ws + 32768000);      // 13,107,200
    uint8_t* s4 = (uint8_t*)(ws + 45875200);      //  3,276,800
    uint8_t* s5 = (uint8_t*)(ws + 49152000);      //  6,553,600 (ends 55,705,600)
    // region @55,705,600: xbuf1 (104,857,600) -> xbuf (52,428,800) ->
    // ypart (33,554,432). Sequentially dead, safe aliases.
    float* xbuf1 = (float*)(ws + 55705600);
    float* xbuf  = (float*)(ws + 55705600);
    float* ypart = (float*)(ws + 55705600);
    float* ysumb = (float*)(ws + 122814464);      //  4,194,304 (ends 127,008,768)
    float* fwT   = (float*)(ws + 160563200);      //  6,553,600 (ends 167,116,800)

    conv1_x<<<12800, 256, 0, stream>>>(spike, c1w, xbuf1);
    scan_spike_t<<<800, 256, 0, stream>>>(xbuf1, s1);
    transpose_w<<<1600, 256, 0, stream>>>(fcw, fwT);

    pool_fused<8, 20, 20><<<200, 256, 0, stream>>>(s1, p1w, s2);
    conv_x_all<8, 16, 1, 20, 20><<<3200, 256, 0, stream>>>(s2, c2w, 100.0f, xbuf);
    scan_spike_t<<<400, 256, 0, stream>>>(xbuf, s3);

    pool_fused<16, 10, 10><<<100, 256, 0, stream>>>(s3, p2w, s4);
    conv_x_all<16, 16, 2, 10, 10><<<1600, 256, 0, stream>>>(s4, c3w, 100.0f, xbuf);
    scan_spike_t<<<200, 256, 0, stream>>>(xbuf, s5);

    fc_gemm<<<2048, 256, 0, stream>>>(s5, fwT, ypart);
    fc_reduce<<<1024, 256, 0, stream>>>((const float4*)ypart, (float4*)ysumb);
    fc_scan_t<<<32, 256, 0, stream>>>(ysumb, out);
}

// Round 12
// 409.639 us; speedup vs baseline: 1.5014x; 1.3134x over previous
//
#include <hip/hip_runtime.h>
#include <stdint.h>

// SNN forward: conv1 -> scan -> pool1(fused) -> conv2 -> scan -> pool2(fused)
// -> conv3 -> scan -> fc -> reduce -> scan.
// Neuron: u=.75u+x; v=.96875v+u; s=(v>=100); v*=(1-s). Spikes u8 in d_ws.
// R8: don't fuse scan into conv (grid collapse + t-coalescing loss).
// R10: register-gather S = VMEM-bound. R11: "wave-uniform W" = scalar-cache
// bound. R9's LDS 8x8 tile sat at the 0.5 B/FLOP LDS+VALU co-limit (87us).
// R12: 16x8 tile -> 0.375 B/FLOP (LDS at 75% of port when VALU at peak).

#define T 128
#define AI 0.75f
#define AV 0.96875f
#define THETA 100.0f

__device__ __forceinline__ void neuron_step(float x, float& u, float& v, float& s) {
    u = AI * u + x;
    v = AV * v + u;
    s = (v >= THETA) ? 1.0f : 0.0f;
    v = v * (1.0f - s);
}

// ---------------- conv1 phase A: x[n][o][h][w][t], lanes over t -------------
__global__ __launch_bounds__(256) void conv1_x(
    const float* __restrict__ in, const float* __restrict__ cw,
    float* __restrict__ xout)
{
    int bid = blockIdx.x;                       // 12800
    int tIdx = (bid % 800) * 256 + threadIdx.x; // within [40][40][128]
    int n = bid / 800;
    int t  = tIdx % T;
    int wx = (tIdx / T) % 40;
    int hy = tIdx / (T * 40);

    float val[18];
    #pragma unroll
    for (int c = 0; c < 2; c++)
      #pragma unroll
      for (int dh = -1; dh <= 1; dh++)
        #pragma unroll
        for (int dw = -1; dw <= 1; dw++) {
            int q = c * 9 + (dh + 1) * 3 + (dw + 1);
            int hh = hy + dh, ww = wx + dw;
            bool ok = (hh >= 0) && (hh < 40) && (ww >= 0) && (ww < 40);
            val[q] = ok ? in[(((n * 2 + c) * 40 + hh) * 40 + ww) * T + t] : 0.0f;
        }

    #pragma unroll 1
    for (int o = 0; o < 8; o++) {
        const float* wp = cw + o * 18;          // uniform -> s_load
        float a = 0.f;
        #pragma unroll
        for (int q = 0; q < 18; q++) a += wp[q] * val[q];
        xout[(((n * 8 + o) * 40 + hy) * 40 + wx) * T + t] = a * 20.0f;
    }
}

// ---------------- scan (transposed via LDS): fp32 x rows -> u8 spikes -------
__global__ __launch_bounds__(256) void scan_spike_t(
    const float* __restrict__ x, uint8_t* __restrict__ out)
{
    __shared__ float lds[256 * 20];
    int tid = threadIdx.x;
    size_t r0 = (size_t)blockIdx.x * 256;
    const float* xb = x + r0 * T;

    float u = 0.f, v = 0.f;
    uint32_t ob[32];

    #pragma unroll
    for (int tb = 0; tb < 8; tb++) {
        __syncthreads();
        #pragma unroll
        for (int k = 0; k < 4; k++) {
            int f = tid + k * 256;
            int row = f >> 2, q = f & 3;
            float4 vv = *(const float4*)(xb + (size_t)row * T + tb * 16 + q * 4);
            *(float4*)&lds[row * 20 + q * 4] = vv;
        }
        __syncthreads();
        #pragma unroll
        for (int k = 0; k < 4; k++) {
            float4 xv = *(const float4*)&lds[tid * 20 + k * 4];
            float s0, s1, s2, s3;
            neuron_step(xv.x, u, v, s0); neuron_step(xv.y, u, v, s1);
            neuron_step(xv.z, u, v, s2); neuron_step(xv.w, u, v, s3);
            ob[tb * 4 + k] = (uint32_t)s0 | ((uint32_t)s1 << 8) |
                             ((uint32_t)s2 << 16) | ((uint32_t)s3 << 24);
        }
    }

    uint32_t* op = (uint32_t*)(out + (r0 + tid) * T);
    #pragma unroll
    for (int k = 0; k < 8; k++)
        *(uint4*)&op[k * 4] = make_uint4(ob[k*4], ob[k*4+1], ob[k*4+2], ob[k*4+3]);
}

// ---------------- pool fused: 2x2 sum (u8 adds, no carry) + scan + delay ----
template<int C, int HO, int WO>
__global__ __launch_bounds__(256) void pool_fused(
    const uint8_t* __restrict__ in, const float* __restrict__ pw_ptr,
    uint8_t* __restrict__ out)
{
    __shared__ uint32_t lds[256 * 20];
    int tid = threadIdx.x;
    size_t r0 = (size_t)blockIdx.x * 256;
    float pw = pw_ptr[0];

    float u = 0.f, v = 0.f;
    uint32_t ob[32];
    uint32_t carry = 0;

    #pragma unroll
    for (int tb = 0; tb < 2; tb++) {
        __syncthreads();
        #pragma unroll
        for (int k = 0; k < 4; k++) {
            int f = tid + k * 256;
            int row = f >> 2, q = f & 3;
            int orow = (int)r0 + row;
            int wx = orow % WO;
            int hy = (orow / WO) % HO;
            int c  = (orow / (WO * HO)) % C;
            int nn = orow / (WO * HO * C);
            const uint8_t* p00 = in +
                (((size_t)(nn * C + c) * (2 * HO) + 2 * hy) * (2 * WO) + 2 * wx) * T;
            int off = tb * 64 + q * 16;
            uint4 a = *(const uint4*)(p00 + off);
            uint4 b = *(const uint4*)(p00 + T + off);
            uint4 cc = *(const uint4*)(p00 + 2 * WO * T + off);
            uint4 d = *(const uint4*)(p00 + 2 * WO * T + T + off);
            *(uint4*)&lds[row * 20 + q * 4] =
                make_uint4(a.x + b.x + cc.x + d.x, a.y + b.y + cc.y + d.y,
                           a.z + b.z + cc.z + d.z, a.w + b.w + cc.w + d.w);
        }
        __syncthreads();
        #pragma unroll
        for (int q = 0; q < 4; q++) {
            uint4 w = *(const uint4*)&lds[tid * 20 + q * 4];
            uint32_t words[4] = {w.x, w.y, w.z, w.w};
            #pragma unroll
            for (int j = 0; j < 4; j++) {
                uint32_t cur = words[j];
                uint32_t del = (cur << 8) | carry;   // delay_shift bytes
                carry = cur >> 24;
                float s0, s1, s2, s3;
                neuron_step(pw * (float)(del & 0xffu),         u, v, s0);
                neuron_step(pw * (float)((del >> 8) & 0xffu),  u, v, s1);
                neuron_step(pw * (float)((del >> 16) & 0xffu), u, v, s2);
                neuron_step(pw * (float)((del >> 24) & 0xffu), u, v, s3);
                ob[tb * 16 + q * 4 + j] = (uint32_t)s0 | ((uint32_t)s1 << 8) |
                                          ((uint32_t)s2 << 16) | ((uint32_t)s3 << 24);
            }
        }
    }

    uint32_t* op = (uint32_t*)(out + (r0 + tid) * T);
    #pragma unroll
    for (int k = 0; k < 8; k++)
        *(uint4*)&op[k * 4] = make_uint4(ob[k*4], ob[k*4+1], ob[k*4+2], ob[k*4+3]);
}

// ---------------- conv phase A (grouped): COUT_PER outputs per thread -------
template<int CIN, int COUT_PER, int G, int H, int W>
__global__ __launch_bounds__(256) void conv_x_all(
    const uint8_t* __restrict__ in, const float* __restrict__ cw, float scale,
    float* __restrict__ xout)
{
    constexpr int BPG = H * W * T / 256;
    int bid = blockIdx.x;
    int tIdx = (bid % BPG) * 256 + threadIdx.x;
    int gn = bid / BPG;
    int g = gn % G;                             // uniform
    int n = gn / G;                             // uniform
    int t  = tIdx % T;
    int wx = (tIdx / T) % W;
    int hy = tIdx / (T * W);

    int tm = (t == 0) ? 0 : (t - 1);
    float tmask = (t == 0) ? 0.0f : 1.0f;

    bool okh[3] = {hy > 0, true, hy < H - 1};
    bool okw[3] = {wx > 0, true, wx < W - 1};

    const uint8_t* base = in + ((n * CIN * H + hy) * W + wx) * T + tm;
    const float* wbase = cw + g * COUT_PER * CIN * 9;

    float acc[COUT_PER];
    #pragma unroll
    for (int oi = 0; oi < COUT_PER; oi++) acc[oi] = 0.f;

    #pragma unroll 1
    for (int c = 0; c < CIN; c++) {
        float tap[9];
        #pragma unroll
        for (int dh = 0; dh < 3; dh++)
            #pragma unroll
            for (int dw = 0; dw < 3; dw++) {
                bool ok = okh[dh] && okw[dw];
                tap[dh * 3 + dw] = ok ?
                    (float)base[(c * H * W + (dh - 1) * W + (dw - 1)) * T] : 0.f;
            }
        #pragma unroll
        for (int oi = 0; oi < COUT_PER; oi++) {
            if ((oi & 3) == 0) __builtin_amdgcn_sched_barrier(0);
            const float* wp = wbase + (oi * CIN + c) * 9;
            float a = acc[oi];
            #pragma unroll
            for (int q = 0; q < 9; q++) a += wp[q] * tap[q];
            acc[oi] = a;
        }
    }

    float sm = scale * tmask;
    #pragma unroll
    for (int oi = 0; oi < COUT_PER; oi++) {
        int o = g * COUT_PER + oi;
        xout[((n * (G * COUT_PER) + o) * H * W + hy * W + wx) * T + t] = acc[oi] * sm;
    }
}

// ---------------- W transpose: fwT[c][o] = fw[o][c] -------------------------
__global__ __launch_bounds__(256) void transpose_w(
    const float* __restrict__ fw, float* __restrict__ fwT)
{
    __shared__ float tile[32][33];
    int bc = blockIdx.x % 100;
    int bo = blockIdx.x / 100;
    int lx = threadIdx.x & 31;
    int ly = threadIdx.x >> 5;
    #pragma unroll
    for (int k = 0; k < 4; k++)
        tile[ly + 8 * k][lx] = fw[(bo * 32 + ly + 8 * k) * 3200 + bc * 32 + lx];
    __syncthreads();
    #pragma unroll
    for (int k = 0; k < 4; k++)
        fwT[(bc * 32 + ly + 8 * k) * 512 + bo * 32 + lx] = tile[lx][ly + 8 * k];
}

// ---------------- FC GEMM: 16x8 thread tile, 128-thr blocks, c-split 16 -----
// B/FLOP = 2*(16+8)/(16*8) = 0.375 -> LDS at 75% of port at VALU peak.
// Grid 1024 = 4 blocks/CU (grid-limit lesson, R7). Reg double-buffer staging.
#define FC_CC 20
#define FC_ROW 140
#define FC_CRANGE 200

__global__ __launch_bounds__(128, 2) void fc_gemm(
    const uint8_t* __restrict__ s5,   // [16][3200][128]
    const float* __restrict__ fwT,    // [3200][512]
    float* __restrict__ ypart)        // [16][16][128][512]
{
    __shared__ float ldsW[FC_CC * FC_ROW];
    __shared__ float ldsS[FC_CC * FC_ROW];

    int bid = blockIdx.x;             // 1024
    int ks = bid & 15;
    int n  = (bid >> 4) & 15;
    int ob = bid >> 8;                // 0..3
    int o0 = ob * 128;
    int cbase = ks * FC_CRANGE;

    int tid = threadIdx.x;            // 128
    int og = tid & 7;                 // 16-o group
    int tg = tid >> 3;                // 0..15 (8-t group)
    int wo = og * 16 + ((og >> 1) << 2);   // swizzled: +4 pad per 32 floats
    int so = tg * 8 + ((tg >> 2) << 2);

    int srow = tid >> 5;              // 0..3 (staging)
    int scol = tid & 31;              // 0..31
    int sw   = scol * 4 + ((scol >> 3) << 2);

    float acc[16][8];
    #pragma unroll
    for (int i = 0; i < 16; i++)
        #pragma unroll
        for (int j = 0; j < 8; j++) acc[i][j] = 0.f;

    float4 wr4[5];
    uint32_t sr4[5];

    {   // preload chunk 0 (rows p*4+srow cover 0..19 exactly)
        #pragma unroll
        for (int p = 0; p < 5; p++) {
            int c = cbase + p * 4 + srow;
            wr4[p] = *(const float4*)(fwT + (size_t)c * 512 + o0 + scol * 4);
            sr4[p] = *(const uint32_t*)(s5 + ((size_t)n * 3200 + c) * T + scol * 4);
        }
    }

    for (int ch = 0; ch < 10; ch++) {
        __syncthreads();
        #pragma unroll
        for (int p = 0; p < 5; p++) {
            int cc = p * 4 + srow;
            *(float4*)&ldsW[cc * FC_ROW + sw] = wr4[p];
            uint32_t raw = sr4[p];
            uint32_t prv = (uint32_t)__shfl_up((int)raw, 1);
            float f0 = (scol == 0) ? 0.f : (float)((prv >> 24) & 0xffu);
            float f1 = (float)(raw & 0xffu);
            float f2 = (float)((raw >> 8) & 0xffu);
            float f3 = (float)((raw >> 16) & 0xffu);
            *(float4*)&ldsS[cc * FC_ROW + sw] = make_float4(f0, f1, f2, f3);
        }
        __syncthreads();
        if (ch < 9) {
            int c0 = cbase + (ch + 1) * FC_CC;
            #pragma unroll
            for (int p = 0; p < 5; p++) {
                int c = c0 + p * 4 + srow;
                wr4[p] = *(const float4*)(fwT + (size_t)c * 512 + o0 + scol * 4);
                sr4[p] = *(const uint32_t*)(s5 + ((size_t)n * 3200 + c) * T + scol * 4);
            }
        }
        #pragma unroll 4
        for (int cc = 0; cc < FC_CC; cc++) {
            const float* wr = &ldsW[cc * FC_ROW + wo];
            const float* sr = &ldsS[cc * FC_ROW + so];
            float4 w0 = *(const float4*)(wr);
            float4 w1 = *(const float4*)(wr + 4);
            float4 w2 = *(const float4*)(wr + 8);
            float4 w3 = *(const float4*)(wr + 12);
            float4 sA = *(const float4*)(sr);
            float4 sB = *(const float4*)(sr + 4);
            float wv[16] = {w0.x, w0.y, w0.z, w0.w, w1.x, w1.y, w1.z, w1.w,
                            w2.x, w2.y, w2.z, w2.w, w3.x, w3.y, w3.z, w3.w};
            float sv[8] = {sA.x, sA.y, sA.z, sA.w, sB.x, sB.y, sB.z, sB.w};
            #pragma unroll
            for (int i = 0; i < 16; i++)
                #pragma unroll
                for (int j = 0; j < 8; j++)
                    acc[i][j] += wv[i] * sv[j];
        }
    }

    float* yp = ypart + ((size_t)(ks * 16 + n) * T) * 512;
    #pragma unroll
    for (int j = 0; j < 8; j++) {
        int t = tg * 8 + j;
        #pragma unroll
        for (int q = 0; q < 4; q++) {
            float4 v0 = make_float4(acc[q*4+0][j], acc[q*4+1][j],
                                    acc[q*4+2][j], acc[q*4+3][j]);
            *(float4*)&yp[t * 512 + o0 + og * 16 + q * 4] = v0;
        }
    }
}

// ---------------- FC partial reduce (16 partials, float4) -------------------
__global__ __launch_bounds__(256) void fc_reduce(
    const float4* __restrict__ yp, float4* __restrict__ ys)
{
    int id = blockIdx.x * 256 + threadIdx.x;          // 262,144
    float4 x = yp[id];
    #pragma unroll
    for (int k = 1; k < 16; k++) {
        float4 y = yp[(size_t)k * 262144 + id];
        x.x += y.x; x.y += y.y; x.z += y.z; x.w += y.w;
    }
    ys[id] = x;
}

__global__ __launch_bounds__(64) void fc_scan(
    const float* __restrict__ ysum,   // [16][128][512]
    float* __restrict__ out)          // [16][512][128]
{
    int id = blockIdx.x * 64 + threadIdx.x;           // 8192
    int o = id & 511;
    int n = id >> 9;
    float u = 0.f, v = 0.f;
    float prev = 0.f;                 // final delay_shift
    for (int tb = 0; tb < T / 4; tb++) {
        float b0, b1, b2, b3;
        float x, s;
        x = ysum[(n * T + tb * 4 + 0) * 512 + o]; neuron_step(x, u, v, s); b0 = prev; prev = s;
        x = ysum[(n * T + tb * 4 + 1) * 512 + o]; neuron_step(x, u, v, s); b1 = prev; prev = s;
        x = ysum[(n * T + tb * 4 + 2) * 512 + o]; neuron_step(x, u, v, s); b2 = prev; prev = s;
        x = ysum[(n * T + tb * 4 + 3) * 512 + o]; neuron_step(x, u, v, s); b3 = prev; prev = s;
        *(float4*)&out[((size_t)(n * 512 + o)) * T + tb * 4] = make_float4(b0, b1, b2, b3);
    }
}

// ---------------- launch ----------------------------------------------------
extern "C" void kernel_launch(void* const* d_in, const int* in_sizes, int n_in,
                              void* d_out, int out_size, void* d_ws, size_t ws_size,
                              hipStream_t stream) {
    const float* spike = (const float*)d_in[0];   // [16][2][40][40][128]
    const float* c1w   = (const float*)d_in[1];   // [8][2][3][3]
    const float* c2w   = (const float*)d_in[2];   // [16][8][3][3]
    const float* c3w   = (const float*)d_in[3];   // [32][16][3][3]
    const float* p1w   = (const float*)d_in[4];   // scalar
    const float* p2w   = (const float*)d_in[5];   // scalar
    const float* fcw   = (const float*)d_in[6];   // [512][3200]
    float* out = (float*)d_out;                   // [16][512][128]

    char* ws = (char*)d_ws;
    // spike buffers
    uint8_t* s1 = (uint8_t*)(ws);                 // 26,214,400
    uint8_t* s2 = (uint8_t*)(ws + 26214400);      //  6,553,600
    uint8_t* s3 = (uint8_t*)(ws + 32768000);      // 13,107,200
    uint8_t* s4 = (uint8_t*)(ws + 45875200);      //  3,276,800
    uint8_t* s5 = (uint8_t*)(ws + 49152000);      //  6,553,600 (ends 55,705,600)
    // region @55,705,600: xbuf1 (104,857,600) -> xbuf (52,428,800) ->
    // ypart (67,108,864). Sequentially dead, safe aliases.
    float* xbuf1 = (float*)(ws + 55705600);
    float* xbuf  = (float*)(ws + 55705600);
    float* ypart = (float*)(ws + 55705600);
    float* ysumb = (float*)(ws + 122814464);      //  4,194,304 (ends 127,008,768)
    float* fwT   = (float*)(ws + 160563200);      //  6,553,600 (ends 167,116,800)

    conv1_x<<<12800, 256, 0, stream>>>(spike, c1w, xbuf1);
    scan_spike_t<<<800, 256, 0, stream>>>(xbuf1, s1);
    transpose_w<<<1600, 256, 0, stream>>>(fcw, fwT);

    pool_fused<8, 20, 20><<<200, 256, 0, stream>>>(s1, p1w, s2);
    conv_x_all<8, 16, 1, 20, 20><<<3200, 256, 0, stream>>>(s2, c2w, 100.0f, xbuf);
    scan_spike_t<<<400, 256, 0, stream>>>(xbuf, s3);

    pool_fused<16, 10, 10><<<100, 256, 0, stream>>>(s3, p2w, s4);
    conv_x_all<16, 16, 2, 10, 10><<<1600, 256, 0, stream>>>(s4, c3w, 100.0f, xbuf);
    scan_spike_t<<<200, 256, 0, stream>>>(xbuf, s5);

    fc_gemm<<<1024, 128, 0, stream>>>(s5, fwT, ypart);
    fc_reduce<<<1024, 256, 0, stream>>>((const float4*)ypart, (float4*)ysumb);
    fc_scan<<<128, 64, 0, stream>>>(ysumb, out);
}

// Round 13
// 400.506 us; speedup vs baseline: 1.5357x; 1.0228x over previous
//
#include <hip/hip_runtime.h>
#include <stdint.h>

// SNN forward: conv1 -> scan -> pool1(fused) -> conv2 -> scan -> pool2(fused)
// -> conv3 -> scan -> fc -> reduce -> scan.
// Neuron: u=.75u+x; v=.96875v+u; s=(v>=100); v*=(1-s). Spikes u8 in d_ws.
// R8: don't fuse scan into conv. R10: register-gather S = VMEM-bound.
// R11: wave-uniform W = scalar-cache bound. R12: 128-thr blocks = 2 waves/SIMD
// starvation. R13: R9 shell (256 thr, 8x8 tile) + S as u8 bytes in LDS
// (ds_read_b64 + v_cvt_f32_ubyte) -> LDS 30cyc vs VALU 144cyc per wave-cc,
// c-split 16 -> 4 waves/SIMD.

#define T 128
#define AI 0.75f
#define AV 0.96875f
#define THETA 100.0f

__device__ __forceinline__ void neuron_step(float x, float& u, float& v, float& s) {
    u = AI * u + x;
    v = AV * v + u;
    s = (v >= THETA) ? 1.0f : 0.0f;
    v = v * (1.0f - s);
}

// ---------------- conv1 phase A: x[n][o][h][w][t], lanes over t -------------
__global__ __launch_bounds__(256) void conv1_x(
    const float* __restrict__ in, const float* __restrict__ cw,
    float* __restrict__ xout)
{
    int bid = blockIdx.x;                       // 12800
    int tIdx = (bid % 800) * 256 + threadIdx.x; // within [40][40][128]
    int n = bid / 800;
    int t  = tIdx % T;
    int wx = (tIdx / T) % 40;
    int hy = tIdx / (T * 40);

    float val[18];
    #pragma unroll
    for (int c = 0; c < 2; c++)
      #pragma unroll
      for (int dh = -1; dh <= 1; dh++)
        #pragma unroll
        for (int dw = -1; dw <= 1; dw++) {
            int q = c * 9 + (dh + 1) * 3 + (dw + 1);
            int hh = hy + dh, ww = wx + dw;
            bool ok = (hh >= 0) && (hh < 40) && (ww >= 0) && (ww < 40);
            val[q] = ok ? in[(((n * 2 + c) * 40 + hh) * 40 + ww) * T + t] : 0.0f;
        }

    #pragma unroll 1
    for (int o = 0; o < 8; o++) {
        const float* wp = cw + o * 18;          // uniform -> s_load
        float a = 0.f;
        #pragma unroll
        for (int q = 0; q < 18; q++) a += wp[q] * val[q];
        xout[(((n * 8 + o) * 40 + hy) * 40 + wx) * T + t] = a * 20.0f;
    }
}

// ---------------- scan (transposed via LDS): fp32 x rows -> u8 spikes -------
__global__ __launch_bounds__(256) void scan_spike_t(
    const float* __restrict__ x, uint8_t* __restrict__ out)
{
    __shared__ float lds[256 * 20];
    int tid = threadIdx.x;
    size_t r0 = (size_t)blockIdx.x * 256;
    const float* xb = x + r0 * T;

    float u = 0.f, v = 0.f;
    uint32_t ob[32];

    #pragma unroll
    for (int tb = 0; tb < 8; tb++) {
        __syncthreads();
        #pragma unroll
        for (int k = 0; k < 4; k++) {
            int f = tid + k * 256;
            int row = f >> 2, q = f & 3;
            float4 vv = *(const float4*)(xb + (size_t)row * T + tb * 16 + q * 4);
            *(float4*)&lds[row * 20 + q * 4] = vv;
        }
        __syncthreads();
        #pragma unroll
        for (int k = 0; k < 4; k++) {
            float4 xv = *(const float4*)&lds[tid * 20 + k * 4];
            float s0, s1, s2, s3;
            neuron_step(xv.x, u, v, s0); neuron_step(xv.y, u, v, s1);
            neuron_step(xv.z, u, v, s2); neuron_step(xv.w, u, v, s3);
            ob[tb * 4 + k] = (uint32_t)s0 | ((uint32_t)s1 << 8) |
                             ((uint32_t)s2 << 16) | ((uint32_t)s3 << 24);
        }
    }

    uint32_t* op = (uint32_t*)(out + (r0 + tid) * T);
    #pragma unroll
    for (int k = 0; k < 8; k++)
        *(uint4*)&op[k * 4] = make_uint4(ob[k*4], ob[k*4+1], ob[k*4+2], ob[k*4+3]);
}

// ---------------- pool fused: 2x2 sum (u8 adds, no carry) + scan + delay ----
template<int C, int HO, int WO>
__global__ __launch_bounds__(256) void pool_fused(
    const uint8_t* __restrict__ in, const float* __restrict__ pw_ptr,
    uint8_t* __restrict__ out)
{
    __shared__ uint32_t lds[256 * 20];
    int tid = threadIdx.x;
    size_t r0 = (size_t)blockIdx.x * 256;
    float pw = pw_ptr[0];

    float u = 0.f, v = 0.f;
    uint32_t ob[32];
    uint32_t carry = 0;

    #pragma unroll
    for (int tb = 0; tb < 2; tb++) {
        __syncthreads();
        #pragma unroll
        for (int k = 0; k < 4; k++) {
            int f = tid + k * 256;
            int row = f >> 2, q = f & 3;
            int orow = (int)r0 + row;
            int wx = orow % WO;
            int hy = (orow / WO) % HO;
            int c  = (orow / (WO * HO)) % C;
            int nn = orow / (WO * HO * C);
            const uint8_t* p00 = in +
                (((size_t)(nn * C + c) * (2 * HO) + 2 * hy) * (2 * WO) + 2 * wx) * T;
            int off = tb * 64 + q * 16;
            uint4 a = *(const uint4*)(p00 + off);
            uint4 b = *(const uint4*)(p00 + T + off);
            uint4 cc = *(const uint4*)(p00 + 2 * WO * T + off);
            uint4 d = *(const uint4*)(p00 + 2 * WO * T + T + off);
            *(uint4*)&lds[row * 20 + q * 4] =
                make_uint4(a.x + b.x + cc.x + d.x, a.y + b.y + cc.y + d.y,
                           a.z + b.z + cc.z + d.z, a.w + b.w + cc.w + d.w);
        }
        __syncthreads();
        #pragma unroll
        for (int q = 0; q < 4; q++) {
            uint4 w = *(const uint4*)&lds[tid * 20 + q * 4];
            uint32_t words[4] = {w.x, w.y, w.z, w.w};
            #pragma unroll
            for (int j = 0; j < 4; j++) {
                uint32_t cur = words[j];
                uint32_t del = (cur << 8) | carry;   // delay_shift bytes
                carry = cur >> 24;
                float s0, s1, s2, s3;
                neuron_step(pw * (float)(del & 0xffu),         u, v, s0);
                neuron_step(pw * (float)((del >> 8) & 0xffu),  u, v, s1);
                neuron_step(pw * (float)((del >> 16) & 0xffu), u, v, s2);
                neuron_step(pw * (float)((del >> 24) & 0xffu), u, v, s3);
                ob[tb * 16 + q * 4 + j] = (uint32_t)s0 | ((uint32_t)s1 << 8) |
                                          ((uint32_t)s2 << 16) | ((uint32_t)s3 << 24);
            }
        }
    }

    uint32_t* op = (uint32_t*)(out + (r0 + tid) * T);
    #pragma unroll
    for (int k = 0; k < 8; k++)
        *(uint4*)&op[k * 4] = make_uint4(ob[k*4], ob[k*4+1], ob[k*4+2], ob[k*4+3]);
}

// ---------------- conv phase A (grouped): COUT_PER outputs per thread -------
template<int CIN, int COUT_PER, int G, int H, int W>
__global__ __launch_bounds__(256) void conv_x_all(
    const uint8_t* __restrict__ in, const float* __restrict__ cw, float scale,
    float* __restrict__ xout)
{
    constexpr int BPG = H * W * T / 256;
    int bid = blockIdx.x;
    int tIdx = (bid % BPG) * 256 + threadIdx.x;
    int gn = bid / BPG;
    int g = gn % G;                             // uniform
    int n = gn / G;                             // uniform
    int t  = tIdx % T;
    int wx = (tIdx / T) % W;
    int hy = tIdx / (T * W);

    int tm = (t == 0) ? 0 : (t - 1);
    float tmask = (t == 0) ? 0.0f : 1.0f;

    bool okh[3] = {hy > 0, true, hy < H - 1};
    bool okw[3] = {wx > 0, true, wx < W - 1};

    const uint8_t* base = in + ((n * CIN * H + hy) * W + wx) * T + tm;
    const float* wbase = cw + g * COUT_PER * CIN * 9;

    float acc[COUT_PER];
    #pragma unroll
    for (int oi = 0; oi < COUT_PER; oi++) acc[oi] = 0.f;

    #pragma unroll 1
    for (int c = 0; c < CIN; c++) {
        float tap[9];
        #pragma unroll
        for (int dh = 0; dh < 3; dh++)
            #pragma unroll
            for (int dw = 0; dw < 3; dw++) {
                bool ok = okh[dh] && okw[dw];
                tap[dh * 3 + dw] = ok ?
                    (float)base[(c * H * W + (dh - 1) * W + (dw - 1)) * T] : 0.f;
            }
        #pragma unroll
        for (int oi = 0; oi < COUT_PER; oi++) {
            if ((oi & 3) == 0) __builtin_amdgcn_sched_barrier(0);
            const float* wp = wbase + (oi * CIN + c) * 9;
            float a = acc[oi];
            #pragma unroll
            for (int q = 0; q < 9; q++) a += wp[q] * tap[q];
            acc[oi] = a;
        }
    }

    float sm = scale * tmask;
    #pragma unroll
    for (int oi = 0; oi < COUT_PER; oi++) {
        int o = g * COUT_PER + oi;
        xout[((n * (G * COUT_PER) + o) * H * W + hy * W + wx) * T + t] = acc[oi] * sm;
    }
}

// ---------------- W transpose: fwT[c][o] = fw[o][c] -------------------------
__global__ __launch_bounds__(256) void transpose_w(
    const float* __restrict__ fw, float* __restrict__ fwT)
{
    __shared__ float tile[32][33];
    int bc = blockIdx.x % 100;
    int bo = blockIdx.x / 100;
    int lx = threadIdx.x & 31;
    int ly = threadIdx.x >> 5;
    #pragma unroll
    for (int k = 0; k < 4; k++)
        tile[ly + 8 * k][lx] = fw[(bo * 32 + ly + 8 * k) * 3200 + bc * 32 + lx];
    __syncthreads();
    #pragma unroll
    for (int k = 0; k < 4; k++)
        fwT[(bc * 32 + ly + 8 * k) * 512 + bo * 32 + lx] = tile[lx][ly + 8 * k];
}

// ---------------- FC GEMM: R9 shell + u8 S in LDS, c-split 16 ---------------
// Per wave-cc: 2 ds_read_b128 (W) + 1 ds_read_b64 (S bytes, broadcast) +
// 8 v_cvt_f32_ubyte + 64 fma -> VALU-bound (LDS port at 83%).
// S LDS rows: delay-shifted u8 words, stride 34 u32 (b64-aligned, 2-way free).
#define FC_CC 40
#define FC_ROW 140
#define FC_SROW 34
#define FC_CRANGE 200

__global__ __launch_bounds__(256) void fc_gemm(
    const uint8_t* __restrict__ s5,   // [16][3200][128]
    const float* __restrict__ fwT,    // [3200][512]
    float* __restrict__ ypart)        // [16][16][128][512]
{
    __shared__ float    ldsW[FC_CC * FC_ROW];
    __shared__ uint32_t ldsS[FC_CC * FC_SROW];

    int bid = blockIdx.x;             // 1024
    int ks = bid & 15;
    int n  = (bid >> 4) & 15;
    int ob = bid >> 8;                // 0..3
    int o0 = ob * 128;
    int cbase = ks * FC_CRANGE;

    int tid = threadIdx.x;
    int og = tid & 15;
    int tg = tid >> 4;
    int wo = og * 8 + ((og >> 2) << 2);

    int srow = tid >> 5;              // 0..7
    int scol = tid & 31;              // 0..31
    int sw   = scol * 4 + ((scol >> 3) << 2);

    float acc[8][8];
    #pragma unroll
    for (int i = 0; i < 8; i++)
        #pragma unroll
        for (int j = 0; j < 8; j++) acc[i][j] = 0.f;

    float4 wr4[5];
    uint32_t sr4[5];

    {   // preload chunk 0 (rows p*8+srow cover 0..39 exactly)
        #pragma unroll
        for (int p = 0; p < 5; p++) {
            int c = cbase + p * 8 + srow;
            wr4[p] = *(const float4*)(fwT + (size_t)c * 512 + o0 + scol * 4);
            sr4[p] = *(const uint32_t*)(s5 + ((size_t)n * 3200 + c) * T + scol * 4);
        }
    }

    for (int ch = 0; ch < 5; ch++) {
        __syncthreads();
        #pragma unroll
        for (int p = 0; p < 5; p++) {
            int cc = p * 8 + srow;
            *(float4*)&ldsW[cc * FC_ROW + sw] = wr4[p];
            uint32_t raw = sr4[p];
            uint32_t prv = (uint32_t)__shfl_up((int)raw, 1);
            // delay-shifted word: bytes = s[4w-1], s[4w], s[4w+1], s[4w+2]
            uint32_t del = (raw << 8) | (scol == 0 ? 0u : (prv >> 24));
            ldsS[cc * FC_SROW + scol] = del;
        }
        __syncthreads();
        if (ch < 4) {
            int c0 = cbase + (ch + 1) * FC_CC;
            #pragma unroll
            for (int p = 0; p < 5; p++) {
                int c = c0 + p * 8 + srow;
                wr4[p] = *(const float4*)(fwT + (size_t)c * 512 + o0 + scol * 4);
                sr4[p] = *(const uint32_t*)(s5 + ((size_t)n * 3200 + c) * T + scol * 4);
            }
        }
        #pragma unroll 4
        for (int cc = 0; cc < FC_CC; cc++) {
            const float* wr = &ldsW[cc * FC_ROW + wo];
            float4 w0 = *(const float4*)(wr);
            float4 w1 = *(const float4*)(wr + 4);
            uint32_t sa = ldsS[cc * FC_SROW + tg * 2];
            uint32_t sb = ldsS[cc * FC_SROW + tg * 2 + 1];
            float wv[8] = {w0.x, w0.y, w0.z, w0.w, w1.x, w1.y, w1.z, w1.w};
            float sv[8] = {(float)(sa & 0xffu), (float)((sa >> 8) & 0xffu),
                           (float)((sa >> 16) & 0xffu), (float)(sa >> 24),
                           (float)(sb & 0xffu), (float)((sb >> 8) & 0xffu),
                           (float)((sb >> 16) & 0xffu), (float)(sb >> 24)};
            #pragma unroll
            for (int i = 0; i < 8; i++)
                #pragma unroll
                for (int j = 0; j < 8; j++)
                    acc[i][j] += wv[i] * sv[j];
        }
    }

    float* yp = ypart + ((size_t)(ks * 16 + n) * T) * 512;
    #pragma unroll
    for (int j = 0; j < 8; j++) {
        int t = tg * 8 + j;
        float4 v0 = make_float4(acc[0][j], acc[1][j], acc[2][j], acc[3][j]);
        float4 v1 = make_float4(acc[4][j], acc[5][j], acc[6][j], acc[7][j]);
        *(float4*)&yp[t * 512 + o0 + og * 8]     = v0;
        *(float4*)&yp[t * 512 + o0 + og * 8 + 4] = v1;
    }
}

// ---------------- FC partial reduce (16 partials, float4) -------------------
__global__ __launch_bounds__(256) void fc_reduce(
    const float4* __restrict__ yp, float4* __restrict__ ys)
{
    int id = blockIdx.x * 256 + threadIdx.x;          // 262,144
    float4 x = yp[id];
    #pragma unroll
    for (int k = 1; k < 16; k++) {
        float4 y = yp[(size_t)k * 262144 + id];
        x.x += y.x; x.y += y.y; x.z += y.z; x.w += y.w;
    }
    ys[id] = x;
}

__global__ __launch_bounds__(64) void fc_scan(
    const float* __restrict__ ysum,   // [16][128][512]
    float* __restrict__ out)          // [16][512][128]
{
    int id = blockIdx.x * 64 + threadIdx.x;           // 8192
    int o = id & 511;
    int n = id >> 9;
    float u = 0.f, v = 0.f;
    float prev = 0.f;                 // final delay_shift
    for (int tb = 0; tb < T / 4; tb++) {
        float b0, b1, b2, b3;
        float x, s;
        x = ysum[(n * T + tb * 4 + 0) * 512 + o]; neuron_step(x, u, v, s); b0 = prev; prev = s;
        x = ysum[(n * T + tb * 4 + 1) * 512 + o]; neuron_step(x, u, v, s); b1 = prev; prev = s;
        x = ysum[(n * T + tb * 4 + 2) * 512 + o]; neuron_step(x, u, v, s); b2 = prev; prev = s;
        x = ysum[(n * T + tb * 4 + 3) * 512 + o]; neuron_step(x, u, v, s); b3 = prev; prev = s;
        *(float4*)&out[((size_t)(n * 512 + o)) * T + tb * 4] = make_float4(b0, b1, b2, b3);
    }
}

// ---------------- launch ----------------------------------------------------
extern "C" void kernel_launch(void* const* d_in, const int* in_sizes, int n_in,
                              void* d_out, int out_size, void* d_ws, size_t ws_size,
                              hipStream_t stream) {
    const float* spike = (const float*)d_in[0];   // [16][2][40][40][128]
    const float* c1w   = (const float*)d_in[1];   // [8][2][3][3]
    const float* c2w   = (const float*)d_in[2];   // [16][8][3][3]
    const float* c3w   = (const float*)d_in[3];   // [32][16][3][3]
    const float* p1w   = (const float*)d_in[4];   // scalar
    const float* p2w   = (const float*)d_in[5];   // scalar
    const float* fcw   = (const float*)d_in[6];   // [512][3200]
    float* out = (float*)d_out;                   // [16][512][128]

    char* ws = (char*)d_ws;
    // spike buffers
    uint8_t* s1 = (uint8_t*)(ws);                 // 26,214,400
    uint8_t* s2 = (uint8_t*)(ws + 26214400);      //  6,553,600
    uint8_t* s3 = (uint8_t*)(ws + 32768000);      // 13,107,200
    uint8_t* s4 = (uint8_t*)(ws + 45875200);      //  3,276,800
    uint8_t* s5 = (uint8_t*)(ws + 49152000);      //  6,553,600 (ends 55,705,600)
    // region @55,705,600: xbuf1 (104,857,600) -> xbuf (52,428,800) ->
    // ypart (67,108,864). Sequentially dead, safe aliases.
    float* xbuf1 = (float*)(ws + 55705600);
    float* xbuf  = (float*)(ws + 55705600);
    float* ypart = (float*)(ws + 55705600);
    float* ysumb = (float*)(ws + 122814464);      //  4,194,304 (ends 127,008,768)
    float* fwT   = (float*)(ws + 160563200);      //  6,553,600 (ends 167,116,800)

    conv1_x<<<12800, 256, 0, stream>>>(spike, c1w, xbuf1);
    scan_spike_t<<<800, 256, 0, stream>>>(xbuf1, s1);
    transpose_w<<<1600, 256, 0, stream>>>(fcw, fwT);

    pool_fused<8, 20, 20><<<200, 256, 0, stream>>>(s1, p1w, s2);
    conv_x_all<8, 16, 1, 20, 20><<<3200, 256, 0, stream>>>(s2, c2w, 100.0f, xbuf);
    scan_spike_t<<<400, 256, 0, stream>>>(xbuf, s3);

    pool_fused<16, 10, 10><<<100, 256, 0, stream>>>(s3, p2w, s4);
    conv_x_all<16, 16, 2, 10, 10><<<1600, 256, 0, stream>>>(s4, c3w, 100.0f, xbuf);
    scan_spike_t<<<200, 256, 0, stream>>>(xbuf, s5);

    fc_gemm<<<1024, 256, 0, stream>>>(s5, fwT, ypart);
    fc_reduce<<<1024, 256, 0, stream>>>((const float4*)ypart, (float4*)ysumb);
    fc_scan<<<128, 64, 0, stream>>>(ysumb, out);
}

// Round 14
// 392.984 us; speedup vs baseline: 1.5651x; 1.0191x over previous
//
#include <hip/hip_runtime.h>
#include <stdint.h>

// SNN forward: conv1 -> scan -> pool1(fused) -> conv2 -> scan -> pool2(fused)
// -> conv3 -> scan -> fc -> reduce+scan(fused).
// Neuron: u=.75u+x; v=.96875v+u; s=(v>=100); v*=(1-s). Spikes u8 in d_ws.
// FC history: R9 shell (fp32 S, split 8) = 87.5us champion. R10 (reg-gather S)
// VMEM-bound, R11 (wave-uniform W) scalar-cache-bound, R12 (128-thr) wave-
// starved, R13 (u8 S LDS, split16) 97us + 2x write amplification. Locked R9.

#define T 128
#define AI 0.75f
#define AV 0.96875f
#define THETA 100.0f

__device__ __forceinline__ void neuron_step(float x, float& u, float& v, float& s) {
    u = AI * u + x;
    v = AV * v + u;
    s = (v >= THETA) ? 1.0f : 0.0f;
    v = v * (1.0f - s);
}

// ---------------- conv1 phase A: x[n][o][h][w][t], lanes over t -------------
__global__ __launch_bounds__(256) void conv1_x(
    const float* __restrict__ in, const float* __restrict__ cw,
    float* __restrict__ xout)
{
    int bid = blockIdx.x;                       // 12800
    int tIdx = (bid % 800) * 256 + threadIdx.x; // within [40][40][128]
    int n = bid / 800;
    int t  = tIdx % T;
    int wx = (tIdx / T) % 40;
    int hy = tIdx / (T * 40);

    float val[18];
    #pragma unroll
    for (int c = 0; c < 2; c++)
      #pragma unroll
      for (int dh = -1; dh <= 1; dh++)
        #pragma unroll
        for (int dw = -1; dw <= 1; dw++) {
            int q = c * 9 + (dh + 1) * 3 + (dw + 1);
            int hh = hy + dh, ww = wx + dw;
            bool ok = (hh >= 0) && (hh < 40) && (ww >= 0) && (ww < 40);
            val[q] = ok ? in[(((n * 2 + c) * 40 + hh) * 40 + ww) * T + t] : 0.0f;
        }

    #pragma unroll 1
    for (int o = 0; o < 8; o++) {
        const float* wp = cw + o * 18;          // uniform -> s_load
        float a = 0.f;
        #pragma unroll
        for (int q = 0; q < 18; q++) a += wp[q] * val[q];
        xout[(((n * 8 + o) * 40 + hy) * 40 + wx) * T + t] = a * 20.0f;
    }
}

// ---------------- scan (transposed via LDS): fp32 x rows -> u8 spikes -------
__global__ __launch_bounds__(256) void scan_spike_t(
    const float* __restrict__ x, uint8_t* __restrict__ out)
{
    __shared__ float lds[256 * 20];
    int tid = threadIdx.x;
    size_t r0 = (size_t)blockIdx.x * 256;
    const float* xb = x + r0 * T;

    float u = 0.f, v = 0.f;
    uint32_t ob[32];

    #pragma unroll
    for (int tb = 0; tb < 8; tb++) {
        __syncthreads();
        #pragma unroll
        for (int k = 0; k < 4; k++) {
            int f = tid + k * 256;
            int row = f >> 2, q = f & 3;
            float4 vv = *(const float4*)(xb + (size_t)row * T + tb * 16 + q * 4);
            *(float4*)&lds[row * 20 + q * 4] = vv;
        }
        __syncthreads();
        #pragma unroll
        for (int k = 0; k < 4; k++) {
            float4 xv = *(const float4*)&lds[tid * 20 + k * 4];
            float s0, s1, s2, s3;
            neuron_step(xv.x, u, v, s0); neuron_step(xv.y, u, v, s1);
            neuron_step(xv.z, u, v, s2); neuron_step(xv.w, u, v, s3);
            ob[tb * 4 + k] = (uint32_t)s0 | ((uint32_t)s1 << 8) |
                             ((uint32_t)s2 << 16) | ((uint32_t)s3 << 24);
        }
    }

    uint32_t* op = (uint32_t*)(out + (r0 + tid) * T);
    #pragma unroll
    for (int k = 0; k < 8; k++)
        *(uint4*)&op[k * 4] = make_uint4(ob[k*4], ob[k*4+1], ob[k*4+2], ob[k*4+3]);
}

// ---------------- pool fused: 2x2 sum (u8 adds, no carry) + scan + delay ----
template<int C, int HO, int WO>
__global__ __launch_bounds__(256) void pool_fused(
    const uint8_t* __restrict__ in, const float* __restrict__ pw_ptr,
    uint8_t* __restrict__ out)
{
    __shared__ uint32_t lds[256 * 20];
    int tid = threadIdx.x;
    size_t r0 = (size_t)blockIdx.x * 256;
    float pw = pw_ptr[0];

    float u = 0.f, v = 0.f;
    uint32_t ob[32];
    uint32_t carry = 0;

    #pragma unroll
    for (int tb = 0; tb < 2; tb++) {
        __syncthreads();
        #pragma unroll
        for (int k = 0; k < 4; k++) {
            int f = tid + k * 256;
            int row = f >> 2, q = f & 3;
            int orow = (int)r0 + row;
            int wx = orow % WO;
            int hy = (orow / WO) % HO;
            int c  = (orow / (WO * HO)) % C;
            int nn = orow / (WO * HO * C);
            const uint8_t* p00 = in +
                (((size_t)(nn * C + c) * (2 * HO) + 2 * hy) * (2 * WO) + 2 * wx) * T;
            int off = tb * 64 + q * 16;
            uint4 a = *(const uint4*)(p00 + off);
            uint4 b = *(const uint4*)(p00 + T + off);
            uint4 cc = *(const uint4*)(p00 + 2 * WO * T + off);
            uint4 d = *(const uint4*)(p00 + 2 * WO * T + T + off);
            *(uint4*)&lds[row * 20 + q * 4] =
                make_uint4(a.x + b.x + cc.x + d.x, a.y + b.y + cc.y + d.y,
                           a.z + b.z + cc.z + d.z, a.w + b.w + cc.w + d.w);
        }
        __syncthreads();
        #pragma unroll
        for (int q = 0; q < 4; q++) {
            uint4 w = *(const uint4*)&lds[tid * 20 + q * 4];
            uint32_t words[4] = {w.x, w.y, w.z, w.w};
            #pragma unroll
            for (int j = 0; j < 4; j++) {
                uint32_t cur = words[j];
                uint32_t del = (cur << 8) | carry;   // delay_shift bytes
                carry = cur >> 24;
                float s0, s1, s2, s3;
                neuron_step(pw * (float)(del & 0xffu),         u, v, s0);
                neuron_step(pw * (float)((del >> 8) & 0xffu),  u, v, s1);
                neuron_step(pw * (float)((del >> 16) & 0xffu), u, v, s2);
                neuron_step(pw * (float)((del >> 24) & 0xffu), u, v, s3);
                ob[tb * 16 + q * 4 + j] = (uint32_t)s0 | ((uint32_t)s1 << 8) |
                                          ((uint32_t)s2 << 16) | ((uint32_t)s3 << 24);
            }
        }
    }

    uint32_t* op = (uint32_t*)(out + (r0 + tid) * T);
    #pragma unroll
    for (int k = 0; k < 8; k++)
        *(uint4*)&op[k * 4] = make_uint4(ob[k*4], ob[k*4+1], ob[k*4+2], ob[k*4+3]);
}

// ---------------- conv phase A (grouped): COUT_PER outputs per thread -------
template<int CIN, int COUT_PER, int G, int H, int W>
__global__ __launch_bounds__(256) void conv_x_all(
    const uint8_t* __restrict__ in, const float* __restrict__ cw, float scale,
    float* __restrict__ xout)
{
    constexpr int BPG = H * W * T / 256;
    int bid = blockIdx.x;
    int tIdx = (bid % BPG) * 256 + threadIdx.x;
    int gn = bid / BPG;
    int g = gn % G;                             // uniform
    int n = gn / G;                             // uniform
    int t  = tIdx % T;
    int wx = (tIdx / T) % W;
    int hy = tIdx / (T * W);

    int tm = (t == 0) ? 0 : (t - 1);
    float tmask = (t == 0) ? 0.0f : 1.0f;

    bool okh[3] = {hy > 0, true, hy < H - 1};
    bool okw[3] = {wx > 0, true, wx < W - 1};

    const uint8_t* base = in + ((n * CIN * H + hy) * W + wx) * T + tm;
    const float* wbase = cw + g * COUT_PER * CIN * 9;

    float acc[COUT_PER];
    #pragma unroll
    for (int oi = 0; oi < COUT_PER; oi++) acc[oi] = 0.f;

    #pragma unroll 1
    for (int c = 0; c < CIN; c++) {
        float tap[9];
        #pragma unroll
        for (int dh = 0; dh < 3; dh++)
            #pragma unroll
            for (int dw = 0; dw < 3; dw++) {
                bool ok = okh[dh] && okw[dw];
                tap[dh * 3 + dw] = ok ?
                    (float)base[(c * H * W + (dh - 1) * W + (dw - 1)) * T] : 0.f;
            }
        #pragma unroll
        for (int oi = 0; oi < COUT_PER; oi++) {
            if ((oi & 3) == 0) __builtin_amdgcn_sched_barrier(0);
            const float* wp = wbase + (oi * CIN + c) * 9;
            float a = acc[oi];
            #pragma unroll
            for (int q = 0; q < 9; q++) a += wp[q] * tap[q];
            acc[oi] = a;
        }
    }

    float sm = scale * tmask;
    #pragma unroll
    for (int oi = 0; oi < COUT_PER; oi++) {
        int o = g * COUT_PER + oi;
        xout[((n * (G * COUT_PER) + o) * H * W + hy * W + wx) * T + t] = acc[oi] * sm;
    }
}

// ---------------- W transpose: fwT[c][o] = fw[o][c] -------------------------
__global__ __launch_bounds__(256) void transpose_w(
    const float* __restrict__ fw, float* __restrict__ fwT)
{
    __shared__ float tile[32][33];
    int bc = blockIdx.x % 100;
    int bo = blockIdx.x / 100;
    int lx = threadIdx.x & 31;
    int ly = threadIdx.x >> 5;
    #pragma unroll
    for (int k = 0; k < 4; k++)
        tile[ly + 8 * k][lx] = fw[(bo * 32 + ly + 8 * k) * 3200 + bc * 32 + lx];
    __syncthreads();
    #pragma unroll
    for (int k = 0; k < 4; k++)
        fwT[(bc * 32 + ly + 8 * k) * 512 + bo * 32 + lx] = tile[lx][ly + 8 * k];
}

// ---------------- FC GEMM (R9 champion): c-split 8, fp32 S, reg dbuf --------
#define FC_CC 40
#define FC_ROW 140
#define FC_CRANGE 400

__global__ __launch_bounds__(256) void fc_gemm(
    const uint8_t* __restrict__ s5,   // [16][3200][128]
    const float* __restrict__ fwT,    // [3200][512]
    float* __restrict__ ypart)        // [8][16][128][512]
{
    __shared__ float ldsW[FC_CC * FC_ROW];
    __shared__ float ldsS[FC_CC * FC_ROW];

    int bid = blockIdx.x;
    int ks = bid & 7;
    int n  = (bid >> 3) & 15;
    int ob = bid >> 7;                // 0..3
    int o0 = ob * 128;
    int cbase = ks * FC_CRANGE;

    int tid = threadIdx.x;
    int og = tid & 15;
    int tg = tid >> 4;
    int wo = og * 8 + ((og >> 2) << 2);
    int so = tg * 8 + ((tg >> 2) << 2);

    int srow = tid >> 5;              // 0..7
    int scol = tid & 31;              // 0..31
    int sw   = scol * 4 + ((scol >> 3) << 2);

    float acc[8][8];
    #pragma unroll
    for (int i = 0; i < 8; i++)
        #pragma unroll
        for (int j = 0; j < 8; j++) acc[i][j] = 0.f;

    float4 wr4[5];
    uint32_t sr4[5];

    {   // preload chunk 0 (rows p*8+srow cover 0..39 exactly)
        #pragma unroll
        for (int p = 0; p < 5; p++) {
            int c = cbase + p * 8 + srow;
            wr4[p] = *(const float4*)(fwT + (size_t)c * 512 + o0 + scol * 4);
            sr4[p] = *(const uint32_t*)(s5 + ((size_t)n * 3200 + c) * T + scol * 4);
        }
    }

    for (int ch = 0; ch < 10; ch++) {
        __syncthreads();
        #pragma unroll
        for (int p = 0; p < 5; p++) {
            int cc = p * 8 + srow;
            *(float4*)&ldsW[cc * FC_ROW + sw] = wr4[p];
            uint32_t raw = sr4[p];
            uint32_t prv = (uint32_t)__shfl_up((int)raw, 1);
            float f0 = (scol == 0) ? 0.f : (float)((prv >> 24) & 0xffu);
            float f1 = (float)(raw & 0xffu);
            float f2 = (float)((raw >> 8) & 0xffu);
            float f3 = (float)((raw >> 16) & 0xffu);
            *(float4*)&ldsS[cc * FC_ROW + sw] = make_float4(f0, f1, f2, f3);
        }
        __syncthreads();
        if (ch < 9) {
            int c0 = cbase + (ch + 1) * FC_CC;
            #pragma unroll
            for (int p = 0; p < 5; p++) {
                int c = c0 + p * 8 + srow;
                wr4[p] = *(const float4*)(fwT + (size_t)c * 512 + o0 + scol * 4);
                sr4[p] = *(const uint32_t*)(s5 + ((size_t)n * 3200 + c) * T + scol * 4);
            }
        }
        #pragma unroll 4
        for (int cc = 0; cc < FC_CC; cc++) {
            const float* wr = &ldsW[cc * FC_ROW];
            const float* sr = &ldsS[cc * FC_ROW];
            float4 w0 = *(const float4*)(wr + wo);
            float4 w1 = *(const float4*)(wr + wo + 4);
            float4 sA = *(const float4*)(sr + so);
            float4 sB = *(const float4*)(sr + so + 4);
            float wv[8] = {w0.x, w0.y, w0.z, w0.w, w1.x, w1.y, w1.z, w1.w};
            float sv[8] = {sA.x, sA.y, sA.z, sA.w, sB.x, sB.y, sB.z, sB.w};
            #pragma unroll
            for (int i = 0; i < 8; i++)
                #pragma unroll
                for (int j = 0; j < 8; j++)
                    acc[i][j] += wv[i] * sv[j];
        }
    }

    float* yp = ypart + ((size_t)(ks * 16 + n) * T) * 512;
    #pragma unroll
    for (int j = 0; j < 8; j++) {
        int t = tg * 8 + j;
        float4 v0 = make_float4(acc[0][j], acc[1][j], acc[2][j], acc[3][j]);
        float4 v1 = make_float4(acc[4][j], acc[5][j], acc[6][j], acc[7][j]);
        *(float4*)&yp[t * 512 + o0 + og * 8]     = v0;
        *(float4*)&yp[t * 512 + o0 + og * 8 + 4] = v1;
    }
}

// ---------------- FC reduce (8 partials) + scan + output delay, fused -------
// thread = (n,o); loads coalesced over o (lanes), per-t 8 strided partials.
__global__ __launch_bounds__(64) void fc_reduce_scan(
    const float* __restrict__ yp,     // [8][16][128][512]
    float* __restrict__ out)          // [16][512][128]
{
    int id = blockIdx.x * 64 + threadIdx.x;   // 8192 (128 blocks)
    int o = id & 511;
    int n = id >> 9;
    const float* base = yp + (size_t)n * 128 * 512 + o;

    float u = 0.f, v = 0.f;
    float prev = 0.f;                 // final delay_shift
    for (int tb = 0; tb < 32; tb++) {
        float ob0, ob1, ob2, ob3;
        #pragma unroll
        for (int j = 0; j < 4; j++) {
            int t = tb * 4 + j;
            float x = 0.f;
            #pragma unroll
            for (int k = 0; k < 8; k++)
                x += base[(size_t)k * (16 * 128 * 512) + t * 512];
            float s;
            neuron_step(x, u, v, s);
            float d = prev; prev = s;
            if (j == 0) ob0 = d; else if (j == 1) ob1 = d;
            else if (j == 2) ob2 = d; else ob3 = d;
        }
        *(float4*)&out[((size_t)(n * 512 + o)) * T + tb * 4] =
            make_float4(ob0, ob1, ob2, ob3);
    }
}

// ---------------- launch ----------------------------------------------------
extern "C" void kernel_launch(void* const* d_in, const int* in_sizes, int n_in,
                              void* d_out, int out_size, void* d_ws, size_t ws_size,
                              hipStream_t stream) {
    const float* spike = (const float*)d_in[0];   // [16][2][40][40][128]
    const float* c1w   = (const float*)d_in[1];   // [8][2][3][3]
    const float* c2w   = (const float*)d_in[2];   // [16][8][3][3]
    const float* c3w   = (const float*)d_in[3];   // [32][16][3][3]
    const float* p1w   = (const float*)d_in[4];   // scalar
    const float* p2w   = (const float*)d_in[5];   // scalar
    const float* fcw   = (const float*)d_in[6];   // [512][3200]
    float* out = (float*)d_out;                   // [16][512][128]

    char* ws = (char*)d_ws;
    // spike buffers
    uint8_t* s1 = (uint8_t*)(ws);                 // 26,214,400
    uint8_t* s2 = (uint8_t*)(ws + 26214400);      //  6,553,600
    uint8_t* s3 = (uint8_t*)(ws + 32768000);      // 13,107,200
    uint8_t* s4 = (uint8_t*)(ws + 45875200);      //  3,276,800
    uint8_t* s5 = (uint8_t*)(ws + 49152000);      //  6,553,600 (ends 55,705,600)
    // region @55,705,600: xbuf1 (104,857,600) -> xbuf (52,428,800) ->
    // ypart (33,554,432). Sequentially dead, safe aliases.
    float* xbuf1 = (float*)(ws + 55705600);
    float* xbuf  = (float*)(ws + 55705600);
    float* ypart = (float*)(ws + 55705600);
    float* fwT   = (float*)(ws + 160563200);      //  6,553,600 (ends 167,116,800)

    conv1_x<<<12800, 256, 0, stream>>>(spike, c1w, xbuf1);
    scan_spike_t<<<800, 256, 0, stream>>>(xbuf1, s1);
    transpose_w<<<1600, 256, 0, stream>>>(fcw, fwT);

    pool_fused<8, 20, 20><<<200, 256, 0, stream>>>(s1, p1w, s2);
    conv_x_all<8, 16, 1, 20, 20><<<3200, 256, 0, stream>>>(s2, c2w, 100.0f, xbuf);
    scan_spike_t<<<400, 256, 0, stream>>>(xbuf, s3);

    pool_fused<16, 10, 10><<<100, 256, 0, stream>>>(s3, p2w, s4);
    conv_x_all<16, 16, 2, 10, 10><<<1600, 256, 0, stream>>>(s4, c3w, 100.0f, xbuf);
    scan_spike_t<<<200, 256, 0, stream>>>(xbuf, s5);

    fc_gemm<<<512, 256, 0, stream>>>(s5, fwT, ypart);
    fc_reduce_scan<<<128, 64, 0, stream>>>(ypart, out);
}